// Round 4
// baseline (554.051 us; speedup 1.0000x reference)
//
#include <hip/hip_runtime.h>
#include <hip/hip_bf16.h>
#include <cstdint>
#include <cstddef>

#define B_ 16
#define TX_ 256
#define TY_ 2048
#define C_ 80
#define H_ 256
#define NEG_ -1e9f
#define NEG_I (int)0xCE6E6B28   // bit pattern of -1e9f
#define CHUNK_ 32
#define NCHUNK_ (TY_ / CHUNK_)  // 64

// async global->LDS: 16B per lane, wave-uniform LDS base + lane*16
#define GLD16(gp, lp) __builtin_amdgcn_global_load_lds( \
    (const __attribute__((address_space(1))) unsigned int*)(gp), \
    (__attribute__((address_space(3))) unsigned int*)(lp), 16, 0, 0)

// ---------------------------------------------------------------------------
// Kernel 1: logp[b,x,t] = -0.5*( S1 - 2*S2 + T3[x] )/C - 0.5*mean_c(ls[x])
// Register tile: 16 x * 4 t per thread. Also emits transposed logp_t [B,Ty,Tx]
// (into the attn slot of d_out) so MAS reads DP columns coalesced.
// ---------------------------------------------------------------------------
__global__ __launch_bounds__(256) void logp_kernel(
    const float* __restrict__ mu, const float* __restrict__ ls,
    const float* __restrict__ y, float* __restrict__ logp_out,
    float* __restrict__ logp_t)
{
    __shared__ float2 coef[16 * 80];
    __shared__ float  aux[16 * 80];
    __shared__ float  Kx[16];
    __shared__ float  yt[16 * 1028];

    const int tid = threadIdx.x;
    const int t0 = blockIdx.x * 1024;
    const int x0 = blockIdx.y * 16;
    const int b  = blockIdx.z;

    for (int i = tid; i < 16 * 80; i += 256) {
        int c = i >> 4, x = i & 15;
        float m = mu[(size_t)(b * C_ + c) * TX_ + x0 + x];
        float l = ls[(size_t)(b * C_ + c) * TX_ + x0 + x];
        float w = __expf(-2.f * l);
        coef[x * 80 + c] = make_float2(w, -2.f * m * w);
        aux[x * 80 + c]  = fmaf(m * m, w, l);
    }
    __syncthreads();
    if (tid < 16) {
        float s = 0.f;
        for (int c = 0; c < C_; ++c) s += aux[tid * 80 + c];
        Kx[tid] = -0.5f * s / (float)C_;
    }

    float acc[16][4];
#pragma unroll
    for (int x = 0; x < 16; ++x)
#pragma unroll
        for (int r = 0; r < 4; ++r) acc[x][r] = 0.f;

    const float4* y4 = (const float4*)y;
    for (int c0 = 0; c0 < C_; c0 += 16) {
        __syncthreads();
        for (int it = 0; it < 16; ++it) {
            int f = tid + it * 256;
            int t = f >> 2, k = f & 3;
            float4 v = y4[(size_t)(b * TY_ + t0 + t) * 20 + (c0 >> 2) + k];
            yt[(4 * k + 0) * 1028 + t] = v.x;
            yt[(4 * k + 1) * 1028 + t] = v.y;
            yt[(4 * k + 2) * 1028 + t] = v.z;
            yt[(4 * k + 3) * 1028 + t] = v.w;
        }
        __syncthreads();
        for (int cl = 0; cl < 16; ++cl) {
            const float4 yv = *reinterpret_cast<const float4*>(&yt[cl * 1028 + 4 * tid]);
            float4 y2 = make_float4(yv.x * yv.x, yv.y * yv.y, yv.z * yv.z, yv.w * yv.w);
#pragma unroll
            for (int x = 0; x < 16; ++x) {
                float2 f2 = coef[x * 80 + c0 + cl];
                acc[x][0] = fmaf(y2.x, f2.x, fmaf(yv.x, f2.y, acc[x][0]));
                acc[x][1] = fmaf(y2.y, f2.x, fmaf(yv.y, f2.y, acc[x][1]));
                acc[x][2] = fmaf(y2.z, f2.x, fmaf(yv.z, f2.y, acc[x][2]));
                acc[x][3] = fmaf(y2.w, f2.x, fmaf(yv.w, f2.y, acc[x][3]));
            }
        }
    }

#pragma unroll
    for (int x = 0; x < 16; ++x) {
        float kx = Kx[x];
#pragma unroll
        for (int r = 0; r < 4; ++r) acc[x][r] = fmaf(acc[x][r], -0.5f / (float)C_, kx);
        float4 out = make_float4(acc[x][0], acc[x][1], acc[x][2], acc[x][3]);
        *reinterpret_cast<float4*>(
            &logp_out[(size_t)(b * TX_ + x0 + x) * TY_ + t0 + 4 * tid]) = out;
    }
#pragma unroll
    for (int r = 0; r < 4; ++r) {
#pragma unroll
        for (int q = 0; q < 4; ++q) {
            float4 out = make_float4(acc[4 * q + 0][r], acc[4 * q + 1][r],
                                     acc[4 * q + 2][r], acc[4 * q + 3][r]);
            *reinterpret_cast<float4*>(
                &logp_t[(size_t)(b * TY_ + t0 + 4 * tid + r) * TX_ + x0 + 4 * q]) = out;
        }
    }
}

// ---------------------------------------------------------------------------
// Kernel 2: MAS, producer/consumer. Block = 128 (2 waves) per batch item.
// Wave 1 (producer): per 32-col chunk issues 32 global_load_lds (each DMAs one
//   1 KiB column: 64 lanes x 16 B) into a 2-slot LDS ring; its pre-barrier
//   vmcnt(0) drain overlaps the consumer's compute on the previous chunk.
// Wave 0 (consumer): per column ds_read_b128 + DPP wave_shr1 carry + DP
//   update; decision nibbles packed 8 cols/dword, streamed to GLOBAL scratch
//   (o_en slot, 64 KiB/b — overwritten later by emit). LDS stays at 64 KiB.
// Backtrace: lane 0 of wave 0, 64-bit row-window with chunk-ahead prefetch.
// ---------------------------------------------------------------------------
__global__ __launch_bounds__(128) void mas_kernel(
    const float* __restrict__ logp_t, const int* __restrict__ xlen,
    const int* __restrict__ ylen, float* __restrict__ dr_out,
    int* __restrict__ idx_out, unsigned int* __restrict__ diag_g)
{
    __shared__ float ring[2][CHUNK_ * 256];   // 65536 B
    const int tid = threadIdx.x;
    const int wave = tid >> 6;
    const int lane = tid & 63;
    const int b = blockIdx.x;
    const int x_len = xlen[b];
    const int y_len = ylen[b];

    float* drb = dr_out + (size_t)b * TX_;
    for (int i = tid; i < TX_; i += 128) drb[i] = 0.f;

    const float* colbase = logp_t + (size_t)b * TY_ * TX_;
    unsigned int* diag = diag_g + (size_t)b * (TY_ / 8) * 64;  // [chunk][word]

    float v0 = (lane == 0) ? 0.f : NEG_, v1 = NEG_, v2 = NEG_, v3 = NEG_;
    unsigned int accb = 0;

    // prologue: producer stages chunk 0
    if (wave == 1) {
        const float* src = colbase + lane * 4;
#pragma unroll
        for (int k = 0; k < CHUNK_; ++k)
            GLD16(src + k * 256, &ring[0][k * 256]);
    }
    __syncthreads();

    for (int n = 0; n < NCHUNK_; ++n) {
        if (wave == 1) {
            if (n + 1 < NCHUNK_) {
                const float* src = colbase + (size_t)(n + 1) * CHUNK_ * 256 + lane * 4;
                float* dst = &ring[(n + 1) & 1][0];
#pragma unroll
                for (int k = 0; k < CHUNK_; ++k)
                    GLD16(src + k * 256, dst + k * 256);
            }
        } else {
            const float* buf = &ring[n & 1][0];
#pragma unroll
            for (int k = 0; k < CHUNK_; ++k) {
                float4 c = *reinterpret_cast<const float4*>(&buf[k * 256 + lane * 4]);
                int shi = __builtin_amdgcn_update_dpp(
                    NEG_I, __float_as_int(v3), 0x138 /*wave_shr1*/, 0xF, 0xF, false);
                float sh0 = __int_as_float(shi);
                accb |= (sh0 > v0) ? (1u << ((k & 7) * 4)) : 0u;
                accb |= (v0 > v1) ? (2u << ((k & 7) * 4)) : 0u;
                accb |= (v1 > v2) ? (4u << ((k & 7) * 4)) : 0u;
                accb |= (v2 > v3) ? (8u << ((k & 7) * 4)) : 0u;
                float m0 = fmaxf(v0, sh0);
                float m1 = fmaxf(v1, v0);
                float m2 = fmaxf(v2, v1);
                float m3 = fmaxf(v3, v2);
                v0 = m0 + c.x; v1 = m1 + c.y; v2 = m2 + c.z; v3 = m3 + c.w;
                if ((k & 7) == 7) {
                    diag[(n * 4 + (k >> 3)) * 64 + lane] = accb;
                    accb = 0;
                }
            }
        }
        __syncthreads();
    }

    // -------- backtrace: lane 0 of wave 0 --------
    if (tid == 0) {
        int i = x_len - 1;
        int cnt = 0;
        int j = y_len - 1;
        int jc = j >> 3;
        int jb = j & 7;
        int p = i >> 3;          // 8-row pair index
        int ep = p;              // pair index at entry of current chunk

        auto pair = [&](int cc, int pp) -> unsigned long long {
            pp = pp < 0 ? 0 : pp;
            uint2 u = *(const uint2*)&diag[cc * 64 + 2 * pp];
            return (unsigned long long)u.x | ((unsigned long long)u.y << 32);
        };

        unsigned long long W  = pair(jc, p);
        unsigned long long Wl = pair(jc, p - 1);
        unsigned long long N  = (jc > 0) ? pair(jc - 1, p) : 0ULL;
        unsigned long long Nl = (jc > 0) ? pair(jc - 1, p - 1) : 0ULL;

        int* ib = idx_out + (size_t)b * TY_;
        while (true) {
            ib[j] = i;
            cnt++;
            int pos = (((i >> 2) & 1) << 5) | (jb << 2) | (i & 3);
            if (((W >> pos) & 1ULL) && i > 0) {
                drb[i] = (float)cnt; cnt = 0; --i;
                if ((i & 7) == 7) {           // crossed 8-row window
                    --p; W = Wl;
                    Wl = pair(jc, p - 1);
                }
            }
            --j; --jb;
            if (jb < 0) {
                if (jc == 0) break;
                --jc; jb = 7;
                W = (p == ep) ? N : Nl;       // p in {ep, ep-1} by construction
                ep = p;
                Wl = pair(jc, p - 1);
                N  = (jc > 0) ? pair(jc - 1, p) : 0ULL;
                Nl = (jc > 0) ? pair(jc - 1, p - 1) : 0ULL;
            }
        }
        drb[i] = (float)cnt;
    }
}

// ---------------------------------------------------------------------------
// Kernel 3: emit attn (one-hot path) and o_en_ex (gather of en rows).
// ---------------------------------------------------------------------------
__global__ __launch_bounds__(256) void emit_kernel(
    const float* __restrict__ en, const int* __restrict__ ylen,
    const int* __restrict__ idx_in, float* __restrict__ o_en,
    float* __restrict__ attn)
{
    const int tid = threadIdx.x;
    const int b = blockIdx.x;
    const int r = blockIdx.y;
    const int y_len = ylen[b];
    const int* ib = idx_in + (size_t)b * TY_;

    if (r < 256) {
        const int x = r;
        float* out = attn + ((size_t)b * TX_ + x) * TY_;
        for (int t = tid; t < TY_; t += 256) {
            int ii = ib[t];
            out[t] = (t < y_len && ii == x) ? 1.f : 0.f;
        }
    } else {
        const int h = r - 256;
        __shared__ float enr[256];
        enr[tid] = en[((size_t)b * H_ + h) * TX_ + tid];
        __syncthreads();
        float* out = o_en + ((size_t)b * H_ + h) * TY_;
        for (int t = tid; t < TY_; t += 256) {
            int ii = ib[t];
            bool a = (t < y_len);
            int is = a ? ii : 0;
            out[t] = a ? enr[is] : 0.f;
        }
    }
}

// ---------------------------------------------------------------------------
extern "C" void kernel_launch(void* const* d_in, const int* in_sizes, int n_in,
                              void* d_out, int out_size, void* d_ws, size_t ws_size,
                              hipStream_t stream)
{
    const float* en = (const float*)d_in[0];
    const float* mu = (const float*)d_in[1];
    const float* ls = (const float*)d_in[2];
    const float* y  = (const float*)d_in[3];
    const int* xl   = (const int*)d_in[4];
    const int* yl   = (const int*)d_in[5];

    float* o_en = (float*)d_out;                       // [16,256,2048]
    float* attn = o_en + (size_t)B_ * TX_ * TY_;       // [16,256,2048]
    float* dr   = attn + (size_t)B_ * TX_ * TY_;       // [16,256]
    float* logp = dr + (size_t)B_ * TX_;               // [16,256,2048]

    float* logp_t = attn;                              // scratch in attn slot
    // diag scratch lives in the o_en slot (1 MB; emit overwrites it later)
    unsigned int* diag_g = (unsigned int*)o_en;
    int* idxArr = (int*)d_ws;                          // [16,2048]

    dim3 g1(2, 16, 16);
    logp_kernel<<<g1, 256, 0, stream>>>(mu, ls, y, logp, logp_t);

    mas_kernel<<<dim3(16), dim3(128), 0, stream>>>(logp_t, xl, yl, dr, idxArr, diag_g);

    dim3 g3(16, 512);
    emit_kernel<<<g3, 256, 0, stream>>>(en, yl, idxArr, o_en, attn);
}

// Round 5
// 468.315 us; speedup vs baseline: 1.1831x; 1.1831x over previous
//
#include <hip/hip_runtime.h>
#include <hip/hip_bf16.h>
#include <cstdint>
#include <cstddef>

#define B_ 16
#define TX_ 256
#define TY_ 2048
#define C_ 80
#define H_ 256
#define NEG_ -1e9f
#define NEG_I (int)0xCE6E6B28   // bit pattern of -1e9f
#define CHUNK_ 32
#define NCHUNK_ (TY_ / CHUNK_)  // 64

// async global->LDS: 16B per lane, wave-uniform LDS base + lane*16
#define GLD16(gp, lp) __builtin_amdgcn_global_load_lds( \
    (const __attribute__((address_space(1))) unsigned int*)(gp), \
    (__attribute__((address_space(3))) unsigned int*)(lp), 16, 0, 0)

// ---------------------------------------------------------------------------
// Kernel 1: logp[b,x,t] = -0.5*( S1 - 2*S2 + T3[x] )/C - 0.5*mean_c(ls[x])
// Register tile: 16 x * 4 t per thread. Also emits transposed logp_t [B,Ty,Tx]
// (into the attn slot of d_out) so MAS reads DP columns coalesced.
// ---------------------------------------------------------------------------
__global__ __launch_bounds__(256) void logp_kernel(
    const float* __restrict__ mu, const float* __restrict__ ls,
    const float* __restrict__ y, float* __restrict__ logp_out,
    float* __restrict__ logp_t)
{
    __shared__ float2 coef[16 * 80];
    __shared__ float  aux[16 * 80];
    __shared__ float  Kx[16];
    __shared__ float  yt[16 * 1028];

    const int tid = threadIdx.x;
    const int t0 = blockIdx.x * 1024;
    const int x0 = blockIdx.y * 16;
    const int b  = blockIdx.z;

    for (int i = tid; i < 16 * 80; i += 256) {
        int c = i >> 4, x = i & 15;
        float m = mu[(size_t)(b * C_ + c) * TX_ + x0 + x];
        float l = ls[(size_t)(b * C_ + c) * TX_ + x0 + x];
        float w = __expf(-2.f * l);
        coef[x * 80 + c] = make_float2(w, -2.f * m * w);
        aux[x * 80 + c]  = fmaf(m * m, w, l);
    }
    __syncthreads();
    if (tid < 16) {
        float s = 0.f;
        for (int c = 0; c < C_; ++c) s += aux[tid * 80 + c];
        Kx[tid] = -0.5f * s / (float)C_;
    }

    float acc[16][4];
#pragma unroll
    for (int x = 0; x < 16; ++x)
#pragma unroll
        for (int r = 0; r < 4; ++r) acc[x][r] = 0.f;

    const float4* y4 = (const float4*)y;
    for (int c0 = 0; c0 < C_; c0 += 16) {
        __syncthreads();
        for (int it = 0; it < 16; ++it) {
            int f = tid + it * 256;
            int t = f >> 2, k = f & 3;
            float4 v = y4[(size_t)(b * TY_ + t0 + t) * 20 + (c0 >> 2) + k];
            yt[(4 * k + 0) * 1028 + t] = v.x;
            yt[(4 * k + 1) * 1028 + t] = v.y;
            yt[(4 * k + 2) * 1028 + t] = v.z;
            yt[(4 * k + 3) * 1028 + t] = v.w;
        }
        __syncthreads();
        for (int cl = 0; cl < 16; ++cl) {
            const float4 yv = *reinterpret_cast<const float4*>(&yt[cl * 1028 + 4 * tid]);
            float4 y2 = make_float4(yv.x * yv.x, yv.y * yv.y, yv.z * yv.z, yv.w * yv.w);
#pragma unroll
            for (int x = 0; x < 16; ++x) {
                float2 f2 = coef[x * 80 + c0 + cl];
                acc[x][0] = fmaf(y2.x, f2.x, fmaf(yv.x, f2.y, acc[x][0]));
                acc[x][1] = fmaf(y2.y, f2.x, fmaf(yv.y, f2.y, acc[x][1]));
                acc[x][2] = fmaf(y2.z, f2.x, fmaf(yv.z, f2.y, acc[x][2]));
                acc[x][3] = fmaf(y2.w, f2.x, fmaf(yv.w, f2.y, acc[x][3]));
            }
        }
    }

#pragma unroll
    for (int x = 0; x < 16; ++x) {
        float kx = Kx[x];
#pragma unroll
        for (int r = 0; r < 4; ++r) acc[x][r] = fmaf(acc[x][r], -0.5f / (float)C_, kx);
        float4 out = make_float4(acc[x][0], acc[x][1], acc[x][2], acc[x][3]);
        *reinterpret_cast<float4*>(
            &logp_out[(size_t)(b * TX_ + x0 + x) * TY_ + t0 + 4 * tid]) = out;
    }
#pragma unroll
    for (int r = 0; r < 4; ++r) {
#pragma unroll
        for (int q = 0; q < 4; ++q) {
            float4 out = make_float4(acc[4 * q + 0][r], acc[4 * q + 1][r],
                                     acc[4 * q + 2][r], acc[4 * q + 3][r]);
            *reinterpret_cast<float4*>(
                &logp_t[(size_t)(b * TY_ + t0 + 4 * tid + r) * TX_ + x0 + 4 * q]) = out;
        }
    }
}

// ---------------------------------------------------------------------------
// Kernel 2a: MAS forward only. Block = 128 (2 waves) per batch item.
// Wave 1 (producer): per 32-col chunk, 32 global_load_lds (1 KiB column each)
// into a 2-slot LDS ring; drain overlaps consumer compute of previous chunk.
// Wave 0 (consumer): ds_read_b128 + DPP wave_shr1 carry + DP update; decision
// nibbles (8 cols/dword) streamed to global scratch (fire-and-forget).
// ---------------------------------------------------------------------------
__global__ __launch_bounds__(128) void mas_fwd_kernel(
    const float* __restrict__ logp_t, unsigned int* __restrict__ diag_g)
{
    __shared__ float ring[2][CHUNK_ * 256];   // 65536 B
    const int tid = threadIdx.x;
    const int wave = tid >> 6;
    const int lane = tid & 63;
    const int b = blockIdx.x;

    const float* colbase = logp_t + (size_t)b * TY_ * TX_;
    unsigned int* diag = diag_g + (size_t)b * (TY_ / 8) * 64;  // [chunk8][word]

    float v0 = (lane == 0) ? 0.f : NEG_, v1 = NEG_, v2 = NEG_, v3 = NEG_;
    unsigned int accb = 0;

    if (wave == 1) {
        const float* src = colbase + lane * 4;
#pragma unroll
        for (int k = 0; k < CHUNK_; ++k)
            GLD16(src + k * 256, &ring[0][k * 256]);
    }
    __syncthreads();

    for (int n = 0; n < NCHUNK_; ++n) {
        if (wave == 1) {
            if (n + 1 < NCHUNK_) {
                const float* src = colbase + (size_t)(n + 1) * CHUNK_ * 256 + lane * 4;
                float* dst = &ring[(n + 1) & 1][0];
#pragma unroll
                for (int k = 0; k < CHUNK_; ++k)
                    GLD16(src + k * 256, dst + k * 256);
            }
        } else {
            const float* buf = &ring[n & 1][0];
#pragma unroll
            for (int k = 0; k < CHUNK_; ++k) {
                float4 c = *reinterpret_cast<const float4*>(&buf[k * 256 + lane * 4]);
                int shi = __builtin_amdgcn_update_dpp(
                    NEG_I, __float_as_int(v3), 0x138 /*wave_shr1*/, 0xF, 0xF, false);
                float sh0 = __int_as_float(shi);
                accb |= (sh0 > v0) ? (1u << ((k & 7) * 4)) : 0u;
                accb |= (v0 > v1) ? (2u << ((k & 7) * 4)) : 0u;
                accb |= (v1 > v2) ? (4u << ((k & 7) * 4)) : 0u;
                accb |= (v2 > v3) ? (8u << ((k & 7) * 4)) : 0u;
                float m0 = fmaxf(v0, sh0);
                float m1 = fmaxf(v1, v0);
                float m2 = fmaxf(v2, v1);
                float m3 = fmaxf(v3, v2);
                v0 = m0 + c.x; v1 = m1 + c.y; v2 = m2 + c.z; v3 = m3 + c.w;
                if ((k & 7) == 7) {
                    diag[(n * 4 + (k >> 3)) * 64 + lane] = accb;
                    accb = 0;
                }
            }
        }
        __syncthreads();
    }
}

// ---------------------------------------------------------------------------
// Kernel 2b: MAS backtrace. 256 threads copy diag (64 KiB) global->LDS, then
// lane 0 runs the 64-bit row-window backtrace from LDS (round-3 proven path).
// ---------------------------------------------------------------------------
__global__ __launch_bounds__(256) void mas_bt_kernel(
    const unsigned int* __restrict__ diag_g, const int* __restrict__ xlen,
    const int* __restrict__ ylen, float* __restrict__ dr_out,
    int* __restrict__ idx_out)
{
    __shared__ unsigned int diag[256 * 64];   // 64 KiB
    const int tid = threadIdx.x;
    const int b = blockIdx.x;
    const int x_len = xlen[b];
    const int y_len = ylen[b];

    float* drb = dr_out + (size_t)b * TX_;
    if (tid < TX_) drb[tid] = 0.f;

    // cooperative copy: 4096 uint4 over 256 threads = 16 iters, coalesced
    const uint4* src = (const uint4*)(diag_g + (size_t)b * (TY_ / 8) * 64);
    uint4* dst = (uint4*)diag;
#pragma unroll
    for (int it = 0; it < 16; ++it)
        dst[tid + it * 256] = src[tid + it * 256];
    __syncthreads();

    if (tid == 0) {
        int i = x_len - 1;
        int cnt = 0;
        int j = y_len - 1;
        int jc = j >> 3;
        int jb = j & 7;
        int p = i >> 3;          // 8-row pair index
        int ep = p;              // pair index at entry of current chunk

        auto pair = [&](int cc, int pp) -> unsigned long long {
            pp = pp < 0 ? 0 : pp;
            uint2 u = *(const uint2*)&diag[cc * 64 + 2 * pp];
            return (unsigned long long)u.x | ((unsigned long long)u.y << 32);
        };

        unsigned long long W  = pair(jc, p);
        unsigned long long Wl = pair(jc, p - 1);
        unsigned long long N  = (jc > 0) ? pair(jc - 1, p) : 0ULL;
        unsigned long long Nl = (jc > 0) ? pair(jc - 1, p - 1) : 0ULL;

        int* ib = idx_out + (size_t)b * TY_;
        while (true) {
            ib[j] = i;
            cnt++;
            int pos = (((i >> 2) & 1) << 5) | (jb << 2) | (i & 3);
            if (((W >> pos) & 1ULL) && i > 0) {
                drb[i] = (float)cnt; cnt = 0; --i;
                if ((i & 7) == 7) {           // crossed 8-row window
                    --p; W = Wl;
                    Wl = pair(jc, p - 1);
                }
            }
            --j; --jb;
            if (jb < 0) {
                if (jc == 0) break;
                --jc; jb = 7;
                W = (p == ep) ? N : Nl;       // p in {ep, ep-1} by construction
                ep = p;
                Wl = pair(jc, p - 1);
                N  = (jc > 0) ? pair(jc - 1, p) : 0ULL;
                Nl = (jc > 0) ? pair(jc - 1, p - 1) : 0ULL;
            }
        }
        drb[i] = (float)cnt;
    }
}

// ---------------------------------------------------------------------------
// Kernel 3: emit attn (one-hot path) and o_en_ex (gather of en rows).
// ---------------------------------------------------------------------------
__global__ __launch_bounds__(256) void emit_kernel(
    const float* __restrict__ en, const int* __restrict__ ylen,
    const int* __restrict__ idx_in, float* __restrict__ o_en,
    float* __restrict__ attn)
{
    const int tid = threadIdx.x;
    const int b = blockIdx.x;
    const int r = blockIdx.y;
    const int y_len = ylen[b];
    const int* ib = idx_in + (size_t)b * TY_;

    if (r < 256) {
        const int x = r;
        float* out = attn + ((size_t)b * TX_ + x) * TY_;
        for (int t = tid; t < TY_; t += 256) {
            int ii = ib[t];
            out[t] = (t < y_len && ii == x) ? 1.f : 0.f;
        }
    } else {
        const int h = r - 256;
        __shared__ float enr[256];
        enr[tid] = en[((size_t)b * H_ + h) * TX_ + tid];
        __syncthreads();
        float* out = o_en + ((size_t)b * H_ + h) * TY_;
        for (int t = tid; t < TY_; t += 256) {
            int ii = ib[t];
            bool a = (t < y_len);
            int is = a ? ii : 0;
            out[t] = a ? enr[is] : 0.f;
        }
    }
}

// ---------------------------------------------------------------------------
extern "C" void kernel_launch(void* const* d_in, const int* in_sizes, int n_in,
                              void* d_out, int out_size, void* d_ws, size_t ws_size,
                              hipStream_t stream)
{
    const float* en = (const float*)d_in[0];
    const float* mu = (const float*)d_in[1];
    const float* ls = (const float*)d_in[2];
    const float* y  = (const float*)d_in[3];
    const int* xl   = (const int*)d_in[4];
    const int* yl   = (const int*)d_in[5];

    float* o_en = (float*)d_out;                       // [16,256,2048]
    float* attn = o_en + (size_t)B_ * TX_ * TY_;       // [16,256,2048]
    float* dr   = attn + (size_t)B_ * TX_ * TY_;       // [16,256]
    float* logp = dr + (size_t)B_ * TX_;               // [16,256,2048]

    float* logp_t = attn;                              // scratch in attn slot
    // diag scratch lives in the o_en slot (1 MB; emit overwrites it later)
    unsigned int* diag_g = (unsigned int*)o_en;
    int* idxArr = (int*)d_ws;                          // [16,2048]

    dim3 g1(2, 16, 16);
    logp_kernel<<<g1, 256, 0, stream>>>(mu, ls, y, logp, logp_t);

    mas_fwd_kernel<<<dim3(16), dim3(128), 0, stream>>>(logp_t, diag_g);
    mas_bt_kernel<<<dim3(16), dim3(256), 0, stream>>>(diag_g, xl, yl, dr, idxArr);

    dim3 g3(16, 512);
    emit_kernel<<<g3, 256, 0, stream>>>(en, yl, idxArr, o_en, attn);
}

// Round 6
// 422.269 us; speedup vs baseline: 1.3121x; 1.1090x over previous
//
#include <hip/hip_runtime.h>
#include <hip/hip_bf16.h>
#include <cstdint>
#include <cstddef>

#define B_ 16
#define TX_ 256
#define TY_ 2048
#define C_ 80
#define H_ 256
#define NEG_ -1e9f
#define NEG_I (int)0xCE6E6B28   // bit pattern of -1e9f
#define CHUNK_ 32
#define NCHUNK_ (TY_ / CHUNK_)  // 64

// async global->LDS: 16B per lane, wave-uniform LDS base + lane*16
#define GLD16(gp, lp) __builtin_amdgcn_global_load_lds( \
    (const __attribute__((address_space(1))) unsigned int*)(gp), \
    (__attribute__((address_space(3))) unsigned int*)(lp), 16, 0, 0)

// ---------------------------------------------------------------------------
// Kernel 1: logp[b,x,t] = -0.5*( S1 - 2*S2 + T3[x] )/C - 0.5*mean_c(ls[x])
// Register tile: 16 x * 4 t per thread. Also emits transposed logp_t [B,Ty,Tx]
// (into the attn slot of d_out) so MAS reads DP columns coalesced.
// ---------------------------------------------------------------------------
__global__ __launch_bounds__(256) void logp_kernel(
    const float* __restrict__ mu, const float* __restrict__ ls,
    const float* __restrict__ y, float* __restrict__ logp_out,
    float* __restrict__ logp_t)
{
    __shared__ float2 coef[16 * 80];
    __shared__ float  aux[16 * 80];
    __shared__ float  Kx[16];
    __shared__ float  yt[16 * 1028];

    const int tid = threadIdx.x;
    const int t0 = blockIdx.x * 1024;
    const int x0 = blockIdx.y * 16;
    const int b  = blockIdx.z;

    for (int i = tid; i < 16 * 80; i += 256) {
        int c = i >> 4, x = i & 15;
        float m = mu[(size_t)(b * C_ + c) * TX_ + x0 + x];
        float l = ls[(size_t)(b * C_ + c) * TX_ + x0 + x];
        float w = __expf(-2.f * l);
        coef[x * 80 + c] = make_float2(w, -2.f * m * w);
        aux[x * 80 + c]  = fmaf(m * m, w, l);
    }
    __syncthreads();
    if (tid < 16) {
        float s = 0.f;
        for (int c = 0; c < C_; ++c) s += aux[tid * 80 + c];
        Kx[tid] = -0.5f * s / (float)C_;
    }

    float acc[16][4];
#pragma unroll
    for (int x = 0; x < 16; ++x)
#pragma unroll
        for (int r = 0; r < 4; ++r) acc[x][r] = 0.f;

    const float4* y4 = (const float4*)y;
    for (int c0 = 0; c0 < C_; c0 += 16) {
        __syncthreads();
        for (int it = 0; it < 16; ++it) {
            int f = tid + it * 256;
            int t = f >> 2, k = f & 3;
            float4 v = y4[(size_t)(b * TY_ + t0 + t) * 20 + (c0 >> 2) + k];
            yt[(4 * k + 0) * 1028 + t] = v.x;
            yt[(4 * k + 1) * 1028 + t] = v.y;
            yt[(4 * k + 2) * 1028 + t] = v.z;
            yt[(4 * k + 3) * 1028 + t] = v.w;
        }
        __syncthreads();
        for (int cl = 0; cl < 16; ++cl) {
            const float4 yv = *reinterpret_cast<const float4*>(&yt[cl * 1028 + 4 * tid]);
            float4 y2 = make_float4(yv.x * yv.x, yv.y * yv.y, yv.z * yv.z, yv.w * yv.w);
#pragma unroll
            for (int x = 0; x < 16; ++x) {
                float2 f2 = coef[x * 80 + c0 + cl];
                acc[x][0] = fmaf(y2.x, f2.x, fmaf(yv.x, f2.y, acc[x][0]));
                acc[x][1] = fmaf(y2.y, f2.x, fmaf(yv.y, f2.y, acc[x][1]));
                acc[x][2] = fmaf(y2.z, f2.x, fmaf(yv.z, f2.y, acc[x][2]));
                acc[x][3] = fmaf(y2.w, f2.x, fmaf(yv.w, f2.y, acc[x][3]));
            }
        }
    }

#pragma unroll
    for (int x = 0; x < 16; ++x) {
        float kx = Kx[x];
#pragma unroll
        for (int r = 0; r < 4; ++r) acc[x][r] = fmaf(acc[x][r], -0.5f / (float)C_, kx);
        float4 out = make_float4(acc[x][0], acc[x][1], acc[x][2], acc[x][3]);
        *reinterpret_cast<float4*>(
            &logp_out[(size_t)(b * TX_ + x0 + x) * TY_ + t0 + 4 * tid]) = out;
    }
#pragma unroll
    for (int r = 0; r < 4; ++r) {
#pragma unroll
        for (int q = 0; q < 4; ++q) {
            float4 out = make_float4(acc[4 * q + 0][r], acc[4 * q + 1][r],
                                     acc[4 * q + 2][r], acc[4 * q + 3][r]);
            *reinterpret_cast<float4*>(
                &logp_t[(size_t)(b * TY_ + t0 + 4 * tid + r) * TX_ + x0 + 4 * q]) = out;
        }
    }
}

// ---------------------------------------------------------------------------
// Kernel 2a: MAS forward only (unchanged from round 5; per-CU-BW-bound).
// ---------------------------------------------------------------------------
__global__ __launch_bounds__(128) void mas_fwd_kernel(
    const float* __restrict__ logp_t, unsigned int* __restrict__ diag_g)
{
    __shared__ float ring[2][CHUNK_ * 256];   // 65536 B
    const int tid = threadIdx.x;
    const int wave = tid >> 6;
    const int lane = tid & 63;
    const int b = blockIdx.x;

    const float* colbase = logp_t + (size_t)b * TY_ * TX_;
    unsigned int* diag = diag_g + (size_t)b * (TY_ / 8) * 64;  // [chunk8][word]

    float v0 = (lane == 0) ? 0.f : NEG_, v1 = NEG_, v2 = NEG_, v3 = NEG_;
    unsigned int accb = 0;

    if (wave == 1) {
        const float* src = colbase + lane * 4;
#pragma unroll
        for (int k = 0; k < CHUNK_; ++k)
            GLD16(src + k * 256, &ring[0][k * 256]);
    }
    __syncthreads();

    for (int n = 0; n < NCHUNK_; ++n) {
        if (wave == 1) {
            if (n + 1 < NCHUNK_) {
                const float* src = colbase + (size_t)(n + 1) * CHUNK_ * 256 + lane * 4;
                float* dst = &ring[(n + 1) & 1][0];
#pragma unroll
                for (int k = 0; k < CHUNK_; ++k)
                    GLD16(src + k * 256, dst + k * 256);
            }
        } else {
            const float* buf = &ring[n & 1][0];
#pragma unroll
            for (int k = 0; k < CHUNK_; ++k) {
                float4 c = *reinterpret_cast<const float4*>(&buf[k * 256 + lane * 4]);
                int shi = __builtin_amdgcn_update_dpp(
                    NEG_I, __float_as_int(v3), 0x138 /*wave_shr1*/, 0xF, 0xF, false);
                float sh0 = __int_as_float(shi);
                accb |= (sh0 > v0) ? (1u << ((k & 7) * 4)) : 0u;
                accb |= (v0 > v1) ? (2u << ((k & 7) * 4)) : 0u;
                accb |= (v1 > v2) ? (4u << ((k & 7) * 4)) : 0u;
                accb |= (v2 > v3) ? (8u << ((k & 7) * 4)) : 0u;
                float m0 = fmaxf(v0, sh0);
                float m1 = fmaxf(v1, v0);
                float m2 = fmaxf(v2, v1);
                float m3 = fmaxf(v3, v2);
                v0 = m0 + c.x; v1 = m1 + c.y; v2 = m2 + c.z; v3 = m3 + c.w;
                if ((k & 7) == 7) {
                    diag[(n * 4 + (k >> 3)) * 64 + lane] = accb;
                    accb = 0;
                }
            }
        }
        __syncthreads();
    }
}

// ---------------------------------------------------------------------------
// Kernel 2b: MAS backtrace, rebuilt. Serial walk on lane 0 but:
//  - window pairs for the NEXT chunk prefetched at chunk start (exit row is
//    provably in {P, P-1}, so 3 pairs cover all cases; branchless select)
//  - 8-step unrolled branchless body (bit extract, cndmask i/pos/window)
//  - path rows buffered and stored 2x int4 per chunk (global) + LDS mirror
//  - dr = histogram of LDS row mirror via 256-thread atomic LDS adds
// ---------------------------------------------------------------------------
__global__ __launch_bounds__(256) void mas_bt_kernel(
    const unsigned int* __restrict__ diag_g, const int* __restrict__ xlen,
    const int* __restrict__ ylen, float* __restrict__ dr_out,
    int* __restrict__ idx_out)
{
    __shared__ unsigned int diag[256 * 64];   // 64 KiB
    __shared__ int rows_l[TY_];               // 8 KiB path-row mirror
    __shared__ int cnt_l[TX_];                // 1 KiB histogram
    const int tid = threadIdx.x;
    const int b = blockIdx.x;
    const int x_len = xlen[b];
    const int y_len = ylen[b];

    cnt_l[tid] = 0;

    // cooperative copy: 4096 uint4 over 256 threads, coalesced
    const uint4* src = (const uint4*)(diag_g + (size_t)b * (TY_ / 8) * 64);
    uint4* dst = (uint4*)diag;
#pragma unroll
    for (int it = 0; it < 16; ++it)
        dst[tid + it * 256] = src[tid + it * 256];
    __syncthreads();

    int* ib = idx_out + (size_t)b * TY_;

    if (tid == 0) {
        auto pairat = [&](int c, int p) -> unsigned long long {
            c = c < 0 ? 0 : c;
            p = p < 0 ? 0 : p;
            return *(const unsigned long long*)&diag[c * 64 + 2 * p];
        };

        int i = x_len - 1;
        const int jc = (y_len - 1) >> 3;
        const int jbtop = (y_len - 1) & 7;

        int P = i >> 3;
        unsigned long long W  = pairat(jc, P);
        unsigned long long Wl = pairat(jc, P - 1);
        // prefetch 3 candidate pairs for chunk jc-1
        unsigned long long n0 = pairat(jc - 1, P);
        unsigned long long n1 = pairat(jc - 1, P - 1);
        unsigned long long n2 = pairat(jc - 1, P - 2);

        // ---- partial top chunk: jb = jbtop..0 (small loop, latency ok) ----
        for (int jb = jbtop; jb >= 0; --jb) {
            ib[8 * jc + jb] = i;
            rows_l[8 * jc + jb] = i;
            int pos = ((i & 4) << 3) | (jb << 2) | (i & 3);
            unsigned bit = ((unsigned)(W >> pos) & 1u) & (unsigned)(i > 0);
            if (bit) {
                --i;
                if ((i & 7) == 7) W = Wl;   // <=1 crossing; Wl stale is fine
            }
        }

        // ---- full chunks c = jc-1 .. 0, 8-step unrolled branchless ----
        for (int c = jc - 1; c >= 0; --c) {
            int p2 = i >> 3;                      // in {P, P-1}
            W  = (p2 == P) ? n0 : n1;
            Wl = (p2 == P) ? n1 : n2;
            P = p2;
            n0 = pairat(c - 1, P);
            n1 = pairat(c - 1, P - 1);
            n2 = pairat(c - 1, P - 2);

            int pos0 = ((i & 4) << 3) | (i & 3);
            int r0, r1, r2, r3, r4, r5, r6, r7;
#define STEP_(JB, RR)                                                         \
            {                                                                 \
                RR = i;                                                       \
                unsigned bit = ((unsigned)(W >> (pos0 + (JB << 2))) & 1u)     \
                             & (unsigned)(i > 0);                             \
                i -= (int)bit;                                                \
                pos0 = ((i & 4) << 3) | (i & 3);                              \
                W = (bit & (unsigned)((i & 7) == 7)) ? Wl : W;                \
            }
            STEP_(7, r7) STEP_(6, r6) STEP_(5, r5) STEP_(4, r4)
            STEP_(3, r3) STEP_(2, r2) STEP_(1, r1) STEP_(0, r0)
#undef STEP_
            int4 lo = make_int4(r0, r1, r2, r3);
            int4 hi = make_int4(r4, r5, r6, r7);
            *reinterpret_cast<int4*>(&ib[8 * c]) = lo;
            *reinterpret_cast<int4*>(&ib[8 * c + 4]) = hi;
            *reinterpret_cast<int4*>(&rows_l[8 * c]) = lo;
            *reinterpret_cast<int4*>(&rows_l[8 * c + 4]) = hi;
        }
    }
    __syncthreads();

    // dr[i] = #{ j < y_len : row(j) == i }  (path visits every row 0..x_len-1)
    for (int t = tid; t < TY_; t += 256)
        if (t < y_len) atomicAdd(&cnt_l[rows_l[t]], 1);
    __syncthreads();
    dr_out[(size_t)b * TX_ + tid] = (float)cnt_l[tid];
}

// ---------------------------------------------------------------------------
// Kernel 3: emit attn (one-hot path) and o_en_ex (gather of en rows).
// ---------------------------------------------------------------------------
__global__ __launch_bounds__(256) void emit_kernel(
    const float* __restrict__ en, const int* __restrict__ ylen,
    const int* __restrict__ idx_in, float* __restrict__ o_en,
    float* __restrict__ attn)
{
    const int tid = threadIdx.x;
    const int b = blockIdx.x;
    const int r = blockIdx.y;
    const int y_len = ylen[b];
    const int* ib = idx_in + (size_t)b * TY_;

    if (r < 256) {
        const int x = r;
        float* out = attn + ((size_t)b * TX_ + x) * TY_;
        for (int t = tid; t < TY_; t += 256) {
            int ii = ib[t];
            out[t] = (t < y_len && ii == x) ? 1.f : 0.f;
        }
    } else {
        const int h = r - 256;
        __shared__ float enr[256];
        enr[tid] = en[((size_t)b * H_ + h) * TX_ + tid];
        __syncthreads();
        float* out = o_en + ((size_t)b * H_ + h) * TY_;
        for (int t = tid; t < TY_; t += 256) {
            int ii = ib[t];
            bool a = (t < y_len);
            int is = a ? ii : 0;
            out[t] = a ? enr[is] : 0.f;
        }
    }
}

// ---------------------------------------------------------------------------
extern "C" void kernel_launch(void* const* d_in, const int* in_sizes, int n_in,
                              void* d_out, int out_size, void* d_ws, size_t ws_size,
                              hipStream_t stream)
{
    const float* en = (const float*)d_in[0];
    const float* mu = (const float*)d_in[1];
    const float* ls = (const float*)d_in[2];
    const float* y  = (const float*)d_in[3];
    const int* xl   = (const int*)d_in[4];
    const int* yl   = (const int*)d_in[5];

    float* o_en = (float*)d_out;                       // [16,256,2048]
    float* attn = o_en + (size_t)B_ * TX_ * TY_;       // [16,256,2048]
    float* dr   = attn + (size_t)B_ * TX_ * TY_;       // [16,256]
    float* logp = dr + (size_t)B_ * TX_;               // [16,256,2048]

    float* logp_t = attn;                              // scratch in attn slot
    // diag scratch lives in the o_en slot (1 MB; emit overwrites it later)
    unsigned int* diag_g = (unsigned int*)o_en;
    int* idxArr = (int*)d_ws;                          // [16,2048]

    dim3 g1(2, 16, 16);
    logp_kernel<<<g1, 256, 0, stream>>>(mu, ls, y, logp, logp_t);

    mas_fwd_kernel<<<dim3(16), dim3(128), 0, stream>>>(logp_t, diag_g);
    mas_bt_kernel<<<dim3(16), dim3(256), 0, stream>>>(diag_g, xl, yl, dr, idxArr);

    dim3 g3(16, 512);
    emit_kernel<<<g3, 256, 0, stream>>>(en, yl, idxArr, o_en, attn);
}

// Round 7
// 323.942 us; speedup vs baseline: 1.7103x; 1.3035x over previous
//
#include <hip/hip_runtime.h>
#include <hip/hip_bf16.h>
#include <cstdint>
#include <cstddef>

#define B_ 16
#define TX_ 256
#define TY_ 2048
#define C_ 80
#define H_ 256
#define NEG_ -1e9f
#define NEG_I (int)0xCE6E6B28   // bit pattern of -1e9f
#define CHUNK_ 32
#define NCHUNK_ (TY_ / CHUNK_)  // 64

// async global->LDS: 16B per lane, wave-uniform LDS base + lane*16
#define GLD16(gp, lp) __builtin_amdgcn_global_load_lds( \
    (const __attribute__((address_space(1))) unsigned int*)(gp), \
    (__attribute__((address_space(3))) unsigned int*)(lp), 16, 0, 0)

// one backtrace step at column-in-chunk jb from row ii, using window pair W
// (rows 8p..8p+7) with fallback Wl (rows 8p-8..8p-1). Proven round-3/6 logic.
#define BT_STEP(JB)                                                           \
    {                                                                         \
        unsigned bit = ((unsigned)(W >> (((ii & 4) << 3) | ((JB) << 2)        \
                                         | (ii & 3))) & 1u)                   \
                     & (unsigned)(ii > 0);                                    \
        ii -= (int)bit;                                                       \
        W = (bit && ((ii & 7) == 7)) ? Wl : W;                                \
    }

// ---------------------------------------------------------------------------
// Kernel 1: logp[b,x,t] = -0.5*( S1 - 2*S2 + T3[x] )/C - 0.5*mean_c(ls[x])
// Register tile: 16 x * 4 t per thread. Also emits transposed logp_t [B,Ty,Tx]
// (into the attn slot of d_out) so MAS reads DP columns coalesced.
// ---------------------------------------------------------------------------
__global__ __launch_bounds__(256) void logp_kernel(
    const float* __restrict__ mu, const float* __restrict__ ls,
    const float* __restrict__ y, float* __restrict__ logp_out,
    float* __restrict__ logp_t)
{
    __shared__ float2 coef[16 * 80];
    __shared__ float  aux[16 * 80];
    __shared__ float  Kx[16];
    __shared__ float  yt[16 * 1028];

    const int tid = threadIdx.x;
    const int t0 = blockIdx.x * 1024;
    const int x0 = blockIdx.y * 16;
    const int b  = blockIdx.z;

    for (int i = tid; i < 16 * 80; i += 256) {
        int c = i >> 4, x = i & 15;
        float m = mu[(size_t)(b * C_ + c) * TX_ + x0 + x];
        float l = ls[(size_t)(b * C_ + c) * TX_ + x0 + x];
        float w = __expf(-2.f * l);
        coef[x * 80 + c] = make_float2(w, -2.f * m * w);
        aux[x * 80 + c]  = fmaf(m * m, w, l);
    }
    __syncthreads();
    if (tid < 16) {
        float s = 0.f;
        for (int c = 0; c < C_; ++c) s += aux[tid * 80 + c];
        Kx[tid] = -0.5f * s / (float)C_;
    }

    float acc[16][4];
#pragma unroll
    for (int x = 0; x < 16; ++x)
#pragma unroll
        for (int r = 0; r < 4; ++r) acc[x][r] = 0.f;

    const float4* y4 = (const float4*)y;
    for (int c0 = 0; c0 < C_; c0 += 16) {
        __syncthreads();
        for (int it = 0; it < 16; ++it) {
            int f = tid + it * 256;
            int t = f >> 2, k = f & 3;
            float4 v = y4[(size_t)(b * TY_ + t0 + t) * 20 + (c0 >> 2) + k];
            yt[(4 * k + 0) * 1028 + t] = v.x;
            yt[(4 * k + 1) * 1028 + t] = v.y;
            yt[(4 * k + 2) * 1028 + t] = v.z;
            yt[(4 * k + 3) * 1028 + t] = v.w;
        }
        __syncthreads();
        for (int cl = 0; cl < 16; ++cl) {
            const float4 yv = *reinterpret_cast<const float4*>(&yt[cl * 1028 + 4 * tid]);
            float4 y2 = make_float4(yv.x * yv.x, yv.y * yv.y, yv.z * yv.z, yv.w * yv.w);
#pragma unroll
            for (int x = 0; x < 16; ++x) {
                float2 f2 = coef[x * 80 + c0 + cl];
                acc[x][0] = fmaf(y2.x, f2.x, fmaf(yv.x, f2.y, acc[x][0]));
                acc[x][1] = fmaf(y2.y, f2.x, fmaf(yv.y, f2.y, acc[x][1]));
                acc[x][2] = fmaf(y2.z, f2.x, fmaf(yv.z, f2.y, acc[x][2]));
                acc[x][3] = fmaf(y2.w, f2.x, fmaf(yv.w, f2.y, acc[x][3]));
            }
        }
    }

#pragma unroll
    for (int x = 0; x < 16; ++x) {
        float kx = Kx[x];
#pragma unroll
        for (int r = 0; r < 4; ++r) acc[x][r] = fmaf(acc[x][r], -0.5f / (float)C_, kx);
        float4 out = make_float4(acc[x][0], acc[x][1], acc[x][2], acc[x][3]);
        *reinterpret_cast<float4*>(
            &logp_out[(size_t)(b * TX_ + x0 + x) * TY_ + t0 + 4 * tid]) = out;
    }
#pragma unroll
    for (int r = 0; r < 4; ++r) {
#pragma unroll
        for (int q = 0; q < 4; ++q) {
            float4 out = make_float4(acc[4 * q + 0][r], acc[4 * q + 1][r],
                                     acc[4 * q + 2][r], acc[4 * q + 3][r]);
            *reinterpret_cast<float4*>(
                &logp_t[(size_t)(b * TY_ + t0 + 4 * tid + r) * TX_ + x0 + 4 * q]) = out;
        }
    }
}

// ---------------------------------------------------------------------------
// Kernel 2a: MAS forward only (unchanged; per-CU-BW-bound, ~115 us).
// ---------------------------------------------------------------------------
__global__ __launch_bounds__(128) void mas_fwd_kernel(
    const float* __restrict__ logp_t, unsigned int* __restrict__ diag_g)
{
    __shared__ float ring[2][CHUNK_ * 256];   // 65536 B
    const int tid = threadIdx.x;
    const int wave = tid >> 6;
    const int lane = tid & 63;
    const int b = blockIdx.x;

    const float* colbase = logp_t + (size_t)b * TY_ * TX_;
    unsigned int* diag = diag_g + (size_t)b * (TY_ / 8) * 64;  // [chunk8][word]

    float v0 = (lane == 0) ? 0.f : NEG_, v1 = NEG_, v2 = NEG_, v3 = NEG_;
    unsigned int accb = 0;

    if (wave == 1) {
        const float* src = colbase + lane * 4;
#pragma unroll
        for (int k = 0; k < CHUNK_; ++k)
            GLD16(src + k * 256, &ring[0][k * 256]);
    }
    __syncthreads();

    for (int n = 0; n < NCHUNK_; ++n) {
        if (wave == 1) {
            if (n + 1 < NCHUNK_) {
                const float* src = colbase + (size_t)(n + 1) * CHUNK_ * 256 + lane * 4;
                float* dst = &ring[(n + 1) & 1][0];
#pragma unroll
                for (int k = 0; k < CHUNK_; ++k)
                    GLD16(src + k * 256, dst + k * 256);
            }
        } else {
            const float* buf = &ring[n & 1][0];
#pragma unroll
            for (int k = 0; k < CHUNK_; ++k) {
                float4 c = *reinterpret_cast<const float4*>(&buf[k * 256 + lane * 4]);
                int shi = __builtin_amdgcn_update_dpp(
                    NEG_I, __float_as_int(v3), 0x138 /*wave_shr1*/, 0xF, 0xF, false);
                float sh0 = __int_as_float(shi);
                accb |= (sh0 > v0) ? (1u << ((k & 7) * 4)) : 0u;
                accb |= (v0 > v1) ? (2u << ((k & 7) * 4)) : 0u;
                accb |= (v1 > v2) ? (4u << ((k & 7) * 4)) : 0u;
                accb |= (v2 > v3) ? (8u << ((k & 7) * 4)) : 0u;
                float m0 = fmaxf(v0, sh0);
                float m1 = fmaxf(v1, v0);
                float m2 = fmaxf(v2, v1);
                float m3 = fmaxf(v3, v2);
                v0 = m0 + c.x; v1 = m1 + c.y; v2 = m2 + c.z; v3 = m3 + c.w;
                if ((k & 7) == 7) {
                    diag[(n * 4 + (k >> 3)) * 64 + lane] = accb;
                    accb = 0;
                }
            }
        }
        __syncthreads();
    }
}

// ---------------------------------------------------------------------------
// Kernel 2b: exit-table build. E_c[i] = row after walking chunk c (8 cols)
// entered at row i. grid (16 chunk-groups, 16 b) x 256 thr -> 256 blocks,
// 16 entries/thread, fully parallel across the whole GPU.
// ---------------------------------------------------------------------------
__global__ __launch_bounds__(256) void mas_tab_kernel(
    const unsigned int* __restrict__ diag_g, unsigned char* __restrict__ E_g)
{
    const int t  = threadIdx.x;        // entry row
    const int cg = blockIdx.x;         // chunk group of 16
    const int b  = blockIdx.y;
    const unsigned int* dg = diag_g + (size_t)b * (TY_ / 8) * 64;
    unsigned char* Eb = E_g + (size_t)b * (TY_ / 8) * 256;
    const int p = t >> 3;

    for (int k = 0; k < 16; ++k) {
        const int c = cg * 16 + k;
        unsigned long long W  = *(const unsigned long long*)&dg[c * 64 + 2 * p];
        unsigned long long Wl = p > 0
            ? *(const unsigned long long*)&dg[c * 64 + 2 * (p - 1)] : 0ULL;
        int ii = t;
#pragma unroll
        for (int jb = 7; jb >= 0; --jb) BT_STEP(jb)
        Eb[c * 256 + t] = (unsigned char)ii;
    }
}

// ---------------------------------------------------------------------------
// Kernel 2c: MAS backtrace via exit tables. Serial part is now only the
// 255-step chunk-entry chain (dependent LDS byte reads); emission of all
// 8-column chunks runs in parallel (1 thread/chunk). dr via LDS histogram.
// ---------------------------------------------------------------------------
__global__ __launch_bounds__(256) void mas_bt_kernel(
    const unsigned int* __restrict__ diag_g, const unsigned char* __restrict__ E_g,
    const int* __restrict__ xlen, const int* __restrict__ ylen,
    float* __restrict__ dr_out, int* __restrict__ idx_out)
{
    __shared__ unsigned char E[256 * 256];      // 64 KiB
    __shared__ unsigned char entry_s[256];
    __shared__ int rows_l[TY_];                 // 8 KiB
    __shared__ int cnt_l[TX_];                  // 1 KiB
    const int tid = threadIdx.x;
    const int b = blockIdx.x;
    const int x_len = xlen[b];
    const int y_len = ylen[b];

    cnt_l[tid] = 0;

    // copy E tables global->LDS, coalesced uint4
    const uint4* srcE = (const uint4*)(E_g + (size_t)b * (TY_ / 8) * 256);
    uint4* dstE = (uint4*)E;
#pragma unroll
    for (int it = 0; it < 16; ++it)
        dstE[tid + it * 256] = srcE[tid + it * 256];
    __syncthreads();

    const unsigned int* dg = diag_g + (size_t)b * (TY_ / 8) * 64;
    int* ib = idx_out + (size_t)b * TY_;
    const int jc = (y_len - 1) >> 3;

    if (tid == 0) {
        // partial top chunk (columns y_len-1 .. 8*jc), serial <=8 steps
        int ii = x_len - 1;
        int p = ii >> 3;
        unsigned long long W  = *(const unsigned long long*)&dg[jc * 64 + 2 * p];
        unsigned long long Wl = p > 0
            ? *(const unsigned long long*)&dg[jc * 64 + 2 * (p - 1)] : 0ULL;
        for (int jb = (y_len - 1) & 7; jb >= 0; --jb) {
            int j = 8 * jc + jb;
            ib[j] = ii; rows_l[j] = ii;
            BT_STEP(jb)
        }
        // entry chain over full chunks: 255 dependent LDS byte reads
        int cur = ii;
        for (int c = jc - 1; c >= 0; --c) {
            entry_s[c] = (unsigned char)cur;
            cur = E[c * 256 + cur];
        }
    }
    __syncthreads();

    // parallel emission: one thread per full chunk
    if (tid < jc) {
        const int c = tid;
        int ii = entry_s[c];
        int p = ii >> 3;
        unsigned long long W  = *(const unsigned long long*)&dg[c * 64 + 2 * p];
        unsigned long long Wl = p > 0
            ? *(const unsigned long long*)&dg[c * 64 + 2 * (p - 1)] : 0ULL;
        int r[8];
#pragma unroll
        for (int jb = 7; jb >= 0; --jb) {
            r[jb] = ii;
            BT_STEP(jb)
        }
        *reinterpret_cast<int4*>(&ib[8 * c])     = make_int4(r[0], r[1], r[2], r[3]);
        *reinterpret_cast<int4*>(&ib[8 * c + 4]) = make_int4(r[4], r[5], r[6], r[7]);
        *reinterpret_cast<int4*>(&rows_l[8 * c])     = make_int4(r[0], r[1], r[2], r[3]);
        *reinterpret_cast<int4*>(&rows_l[8 * c + 4]) = make_int4(r[4], r[5], r[6], r[7]);
    }
    __syncthreads();

    // dr[i] = #{ j < y_len : row(j) == i }
    for (int t = tid; t < TY_; t += 256)
        if (t < y_len) atomicAdd(&cnt_l[rows_l[t]], 1);
    __syncthreads();
    dr_out[(size_t)b * TX_ + tid] = (float)cnt_l[tid];
}

// ---------------------------------------------------------------------------
// Kernel 3: emit attn (one-hot path) and o_en_ex (gather of en rows).
// ---------------------------------------------------------------------------
__global__ __launch_bounds__(256) void emit_kernel(
    const float* __restrict__ en, const int* __restrict__ ylen,
    const int* __restrict__ idx_in, float* __restrict__ o_en,
    float* __restrict__ attn)
{
    const int tid = threadIdx.x;
    const int b = blockIdx.x;
    const int r = blockIdx.y;
    const int y_len = ylen[b];
    const int* ib = idx_in + (size_t)b * TY_;

    if (r < 256) {
        const int x = r;
        float* out = attn + ((size_t)b * TX_ + x) * TY_;
        for (int t = tid; t < TY_; t += 256) {
            int ii = ib[t];
            out[t] = (t < y_len && ii == x) ? 1.f : 0.f;
        }
    } else {
        const int h = r - 256;
        __shared__ float enr[256];
        enr[tid] = en[((size_t)b * H_ + h) * TX_ + tid];
        __syncthreads();
        float* out = o_en + ((size_t)b * H_ + h) * TY_;
        for (int t = tid; t < TY_; t += 256) {
            int ii = ib[t];
            bool a = (t < y_len);
            int is = a ? ii : 0;
            out[t] = a ? enr[is] : 0.f;
        }
    }
}

// ---------------------------------------------------------------------------
extern "C" void kernel_launch(void* const* d_in, const int* in_sizes, int n_in,
                              void* d_out, int out_size, void* d_ws, size_t ws_size,
                              hipStream_t stream)
{
    const float* en = (const float*)d_in[0];
    const float* mu = (const float*)d_in[1];
    const float* ls = (const float*)d_in[2];
    const float* y  = (const float*)d_in[3];
    const int* xl   = (const int*)d_in[4];
    const int* yl   = (const int*)d_in[5];

    float* o_en = (float*)d_out;                       // [16,256,2048]
    float* attn = o_en + (size_t)B_ * TX_ * TY_;       // [16,256,2048]
    float* dr   = attn + (size_t)B_ * TX_ * TY_;       // [16,256]
    float* logp = dr + (size_t)B_ * TX_;               // [16,256,2048]

    float* logp_t = attn;                              // scratch in attn slot
    // diag scratch in the o_en slot (1 MB; emit overwrites later)
    unsigned int* diag_g = (unsigned int*)o_en;
    // exit tables E in the logp_t region (dead after mas_fwd; 1 MB)
    unsigned char* E_g = (unsigned char*)logp_t;
    int* idxArr = (int*)d_ws;                          // [16,2048]

    dim3 g1(2, 16, 16);
    logp_kernel<<<g1, 256, 0, stream>>>(mu, ls, y, logp, logp_t);

    mas_fwd_kernel<<<dim3(16), dim3(128), 0, stream>>>(logp_t, diag_g);
    mas_tab_kernel<<<dim3(16, 16), dim3(256), 0, stream>>>(diag_g, E_g);
    mas_bt_kernel<<<dim3(16), dim3(256), 0, stream>>>(diag_g, E_g, xl, yl, dr, idxArr);

    dim3 g3(16, 512);
    emit_kernel<<<g3, 256, 0, stream>>>(en, yl, idxArr, o_en, attn);
}